// Round 14
// baseline (1418.223 us; speedup 1.0000x reference)
//
#include <hip/hip_runtime.h>

#define B_N 32768
#define D_N 512
#define K_N 8192
#define EMA 0.99f
#define ONE_M_EMA 0.01f
#define EPS_ 1e-5f
#define CCOST 0.25f

// ws layout (fast path):
// [0, 262144)            : u64 packed[B_N]  (low32 = idx), init 0xFF
// [262144, 294912)       : float wsq[K_N]
// [294912, 294920)       : float loss_sum, n_sum
// [295936, +67108864)    : ushort zp[32][32768][32]  {hi:0-15, lo:16-31}, chunk-XOR swizzled
// [67404800, +16777216)  : ushort wp[32][8192][32]   {hi:0-15, lo:16-31}
// Logical K' = 1536 = 48 slices; z sections [hi|hi|lo], w sections [hi|lo|hi]
// realized by slice->physical mapping at stage time.
#define ZP_OFF 295936ull
#define WP_OFF 67404800ull
#define WS_NEED (WP_OFF + 16777216ull)
#define CNT_OFF    295936ull
#define OFFS_OFF   332800ull
#define CURS_OFF   365568ull
#define ROWL_OFF   398336ull
#define LPART_OFF  529408ull

typedef __attribute__((ext_vector_type(8))) short bf16x8;
typedef __attribute__((ext_vector_type(4))) float f32x4;

// ---------------------------------------------------------------- prep ----
// (fallback path only; fast path gets wsq from split_w)
__global__ __launch_bounds__(256) void prep_kernel(const float* __restrict__ w,
                                                   const float* __restrict__ ecs,
                                                   float* __restrict__ wsq,
                                                   float* __restrict__ ncs_out) {
  int row  = blockIdx.x * 4 + (threadIdx.x >> 6);
  int lane = threadIdx.x & 63;
  const float* p = w + (size_t)row * D_N + lane * 8;
  float4 a = *(const float4*)p;
  float4 b = *(const float4*)(p + 4);
  float s = a.x*a.x + a.y*a.y + a.z*a.z + a.w*a.w
          + b.x*b.x + b.y*b.y + b.z*b.z + b.w*b.w;
  #pragma unroll
  for (int off = 32; off; off >>= 1) s += __shfl_down(s, off);
  if (lane == 0) wsq[row] = s;

  int gid = blockIdx.x * 256 + threadIdx.x;
  if (gid < K_N) ncs_out[gid] = EMA * ecs[gid];
}

__global__ __launch_bounds__(256) void prep_nedw(const float4* __restrict__ edw,
                                                 float4* __restrict__ nedw) {
  int i = blockIdx.x * 256 + threadIdx.x;
  float4 v = edw[i];
  v.x *= EMA; v.y *= EMA; v.z *= EMA; v.w *= EMA;
  nedw[i] = v;
}

// ------------------------------------------------------------ pre-split ---
// x[R][512] f32 -> xp[32][R][32] bf16: physical sec0 = hi slices, sec1 = lo.
// 16B chunk stored at (c ^ ((row>>1)&3)) -- ds_read-side XOR swizzle baked in.
__global__ __launch_bounds__(256) void split_z(const float* __restrict__ x,
                                               ushort* __restrict__ xp) {
  int g   = blockIdx.x * 256 + threadIdx.x;
  int row = g >> 6, c = g & 63;
  const float* src = x + (size_t)row * 512 + c * 8;
  float v[8];
  *(float4*)&v[0] = *(const float4*)&src[0];
  *(float4*)&v[4] = *(const float4*)&src[4];
  uint hw[4], lw[4];
  #pragma unroll
  for (int i = 0; i < 4; i++) {
    uint b0 = __float_as_uint(v[2*i]);
    uint b1 = __float_as_uint(v[2*i+1]);
    float r0 = v[2*i]   - __uint_as_float(b0 & 0xFFFF0000u);
    float r1 = v[2*i+1] - __uint_as_float(b1 & 0xFFFF0000u);
    hw[i] = (b0 >> 16) | (b1 & 0xFFFF0000u);
    lw[i] = (__float_as_uint(r0) >> 16) | (__float_as_uint(r1) & 0xFFFF0000u);
  }
  int si  = c >> 2;
  int p   = (c & 3) ^ ((row >> 1) & 3);
  size_t sstr = (size_t)B_N * 32;
  size_t base = (size_t)row * 32 + (size_t)p * 8;
  *(uint4*)&xp[(size_t)si * sstr + base]        = (uint4){hw[0], hw[1], hw[2], hw[3]};
  *(uint4*)&xp[(size_t)(16 + si) * sstr + base] = (uint4){lw[0], lw[1], lw[2], lw[3]};
}

// split_w also computes wsq (fused w pass; one wave per row)
__global__ __launch_bounds__(256) void split_w(const float* __restrict__ x,
                                               ushort* __restrict__ xp,
                                               float* __restrict__ wsq) {
  int g   = blockIdx.x * 256 + threadIdx.x;
  int row = g >> 6, c = g & 63;
  const float* src = x + (size_t)row * 512 + c * 8;
  float v[8];
  *(float4*)&v[0] = *(const float4*)&src[0];
  *(float4*)&v[4] = *(const float4*)&src[4];
  uint hw[4], lw[4]; float w2 = 0.f;
  #pragma unroll
  for (int i = 0; i < 4; i++) {
    uint b0 = __float_as_uint(v[2*i]);
    uint b1 = __float_as_uint(v[2*i+1]);
    float r0 = v[2*i]   - __uint_as_float(b0 & 0xFFFF0000u);
    float r1 = v[2*i+1] - __uint_as_float(b1 & 0xFFFF0000u);
    hw[i] = (b0 >> 16) | (b1 & 0xFFFF0000u);
    lw[i] = (__float_as_uint(r0) >> 16) | (__float_as_uint(r1) & 0xFFFF0000u);
    w2 += v[2*i]*v[2*i] + v[2*i+1]*v[2*i+1];
  }
  int si  = c >> 2;
  int p   = (c & 3) ^ ((row >> 1) & 3);
  size_t sstr = (size_t)K_N * 32;
  size_t base = (size_t)row * 32 + (size_t)p * 8;
  *(uint4*)&xp[(size_t)si * sstr + base]        = (uint4){hw[0], hw[1], hw[2], hw[3]};
  *(uint4*)&xp[(size_t)(16 + si) * sstr + base] = (uint4){lw[0], lw[1], lw[2], lw[3]};
  #pragma unroll
  for (int off = 32; off; off >>= 1) w2 += __shfl_down(w2, off);
  if (c == 0) wsq[row] = w2;
}

// --------------------------------------------------------- score+argmin ---
// score5: ZERO-BARRIER one-wave blocks. 64x128 tile/wave, private ring-2 LDS
// (A 4KB + B 8KB per slot = 24 KB -> 6 independent blocks/CU). All sync is
// per-wave vmcnt/lgkmcnt; no s_barrier in the main loop. Block sweeps 16
// col-tiles x 48 slices (grid.y=4 col-groups). Frag E/O double-buffer.
// FIXES vs r13: per-lane global source in zA/wB; B col-tile stride 8192.
constexpr int CT5 = 16;                     // col-tiles per block (2048 cols)
constexpr int NS5 = CT5 * 48;               // 768 slices per block

#define GLDS(SRC, DST) __builtin_amdgcn_global_load_lds((const unsigned int*)(SRC), (unsigned int*)(DST), 16, 0, 0)

// stage logical slice sf (of col-tile ctf) into slot SL: A 4 ops + B 8 ops.
// zA/wB are per-lane base addresses (lane covers 16 rows x 4 chunks per op).
#define STAGE5(SL)                                                             \
  {                                                                            \
    const int zsl_ = (sf < 32) ? (sf & 15) : (sf - 16);  /* [hi|hi|lo] */      \
    const int wsl_ = (sf < 32) ? sf : (sf - 32);         /* [hi|lo|hi] */      \
    const char* za_ = zA + (size_t)zsl_ * 2097152;                             \
    _Pragma("unroll")                                                          \
    for (int o_ = 0; o_ < 4; o_++)                                             \
      GLDS(za_ + o_ * 1024, (char*)As[SL] + o_ * 1024);                        \
    const char* wb_ = wB + (size_t)wsl_ * 524288 + (size_t)ctf * 8192;         \
    _Pragma("unroll")                                                          \
    for (int o_ = 0; o_ < 8; o_++)                                             \
      GLDS(wb_ + o_ * 1024, (char*)Bs[SL] + o_ * 1024);                        \
    sf++; if (sf == 48) { sf = 0; ctf++; }                                     \
  }

#define LOADFRAG5(AX, BX, RS)                                                  \
  {                                                                            \
    const char* Ab_ = (const char*)As[RS] + aoff;                              \
    const char* Bb_ = (const char*)Bs[RS] + boff;                              \
    _Pragma("unroll")                                                          \
    for (int i_ = 0; i_ < 4; i_++) AX[i_] = *(const bf16x8*)(Ab_ + i_ * 1024); \
    _Pragma("unroll")                                                          \
    for (int j_ = 0; j_ < 8; j_++) BX[j_] = *(const bf16x8*)(Bb_ + j_ * 1024); \
  }

#define MFMABLK5(AX, BX)                                                       \
  {                                                                            \
    __builtin_amdgcn_s_setprio(1);                                             \
    _Pragma("unroll")                                                          \
    for (int i_ = 0; i_ < 4; i_++)                                             \
      _Pragma("unroll")                                                        \
      for (int j_ = 0; j_ < 8; j_++)                                           \
        acc[i_][j_] = __builtin_amdgcn_mfma_f32_16x16x32_bf16(AX[i_], BX[j_],  \
                                                        acc[i_][j_], 0, 0, 0); \
    __builtin_amdgcn_s_setprio(0);                                             \
  }

// iteration g (0..NS5-1): stage g+2 into slot g&1; vmcnt(12): slice g+1
// landed; ds_read frags(g+1) into alternate set; MFMA(g) on current set;
// lgkm(0) drains frag reads (hidden under MFMA); sched_barrier pins order.
#define PH5(AC, BC, AL, BL, G)                                                 \
  {                                                                            \
    const int g_ = (G);                                                        \
    if (g_ + 2 < NS5) STAGE5(g_ & 1)                                           \
    if (g_ + 1 < NS5) {                                                        \
      if (g_ + 2 < NS5) { asm volatile("s_waitcnt vmcnt(12)" ::: "memory"); }  \
      else              { asm volatile("s_waitcnt vmcnt(0)"  ::: "memory"); }  \
      LOADFRAG5(AL, BL, (g_ + 1) & 1)                                          \
    }                                                                          \
    MFMABLK5(AC, BC)                                                           \
    asm volatile("s_waitcnt lgkmcnt(0)" ::: "memory");                         \
    __builtin_amdgcn_sched_barrier(0);                                         \
  }

__global__ __launch_bounds__(64, 2) void score5(
    const ushort* __restrict__ zp, const ushort* __restrict__ wp,
    const float* __restrict__ wsq, unsigned long long* __restrict__ packed) {
  __shared__ ushort As[2][2048];             // 2 slots x [64 rows][32 sh] = 8 KB
  __shared__ ushort Bs[2][4096];             // 2 slots x [128 cols][32 sh] = 16 KB

  const int lane = threadIdx.x;
  const int l15 = lane & 15, lg = (lane >> 4) & 3;
  const int row0 = blockIdx.x * 64;
  const int cg0  = blockIdx.y * 2048;

  // per-lane staging sources: lane covers row (base + o*16 + (lane>>2)), chunk (lane&3)
  const char* zA = (const char*)zp + ((size_t)(row0 + (lane >> 2)) * 64 + (size_t)(lane & 3) * 16);
  const char* wB = (const char*)wp + ((size_t)(cg0  + (lane >> 2)) * 64 + (size_t)(lane & 3) * 16);

  const int swz  = (l15 >> 1) & 3;
  const int aoff = l15 * 64 + ((lg ^ swz) * 16);         // + i*1024 for row-block i
  const int boff = l15 * 64 + ((lg ^ swz) * 16);         // + j*1024 for col-block j

  float rmin[16]; int ridx[16];
  #pragma unroll
  for (int e = 0; e < 16; e++) { rmin[e] = 3.4e38f; ridx[e] = 0; }

  int sf = 0, ctf = 0;                        // staging stream counters
  // prologue: stage slices 0,1; wait slice0; preload frags E(0)
  STAGE5(0)
  STAGE5(1)
  asm volatile("s_waitcnt vmcnt(12)" ::: "memory");
  bf16x8 aE[4], bE[8], aO[4], bO[8];
  LOADFRAG5(aE, bE, 0)
  asm volatile("s_waitcnt lgkmcnt(0)" ::: "memory");
  __builtin_amdgcn_sched_barrier(0);

  for (int ct = 0; ct < CT5; ct++) {
    f32x4 acc[4][8];
    #pragma unroll
    for (int i = 0; i < 4; i++)
      #pragma unroll
      for (int j = 0; j < 8; j++) acc[i][j] = (f32x4){0.f, 0.f, 0.f, 0.f};

    for (int p = 0; p < 24; p++) {            // 24 x 2 iterations = 48 slices
      const int g = ct * 48 + 2 * p;
      PH5(aE, bE, aO, bO, g)                  // even: compute E, load O
      PH5(aO, bO, aE, bE, g + 1)              // odd:  compute O, load E
    }

    // ---- epilogue: distances + running argmin (wsq from global, hot cache)
    float wq[8];
    #pragma unroll
    for (int j = 0; j < 8; j++) wq[j] = wsq[cg0 + ct * 128 + j * 16 + l15];
    #pragma unroll
    for (int i = 0; i < 4; i++)
      #pragma unroll
      for (int r = 0; r < 4; r++) {
        const int e = i * 4 + r;
        #pragma unroll
        for (int j = 0; j < 8; j++) {
          float dist = wq[j] - 2.0f * acc[i][j][r];
          int c = cg0 + ct * 128 + j * 16 + l15;
          if (dist < rmin[e]) { rmin[e] = dist; ridx[e] = c; }  // first idx wins
        }
      }
  }

  // butterfly reduce across the 16 lanes sharing each row
  #pragma unroll
  for (int e = 0; e < 16; e++) {
    float v = rmin[e]; int ix = ridx[e];
    #pragma unroll
    for (int m = 1; m < 16; m <<= 1) {
      float ov = __shfl_xor(v, m, 64);
      int   oi = __shfl_xor(ix, m, 64);
      if (ov < v || (ov == v && oi < ix)) { v = ov; ix = oi; }
    }
    rmin[e] = v; ridx[e] = ix;
  }
  const int s = l15;                          // lane l15 commits entry l15
  float bv = 0.f; int bi = 0;
  #pragma unroll
  for (int e = 0; e < 16; e++) {              // static-index select (rule #20)
    bool p = (e == s);
    bv = p ? rmin[e] : bv;
    bi = p ? ridx[e] : bi;
  }
  unsigned u = __float_as_uint(bv);
  u = (u & 0x80000000u) ? ~u : (u | 0x80000000u);
  unsigned long long key = ((unsigned long long)u << 32) | (unsigned)bi;
  atomicMin(&packed[row0 + (s >> 2) * 16 + lg * 4 + (s & 3)], key);
}

// ---------------------------------------- fallback score (round-2 kernel) --
constexpr int LDP = 40;
constexpr int KSPLIT = 8, COLT = K_N / KSPLIT / 128;
__device__ __forceinline__ void stage16(const float* __restrict__ g,
                                        ushort* __restrict__ h,
                                        ushort* __restrict__ l) {
  float v[16];
  *(float4*)&v[0]  = *(const float4*)&g[0];
  *(float4*)&v[4]  = *(const float4*)&g[4];
  *(float4*)&v[8]  = *(const float4*)&g[8];
  *(float4*)&v[12] = *(const float4*)&g[12];
  uint hw[8], lw[8];
  #pragma unroll
  for (int i = 0; i < 8; i++) {
    uint b0 = __float_as_uint(v[2*i]);
    uint b1 = __float_as_uint(v[2*i+1]);
    float r0 = v[2*i]   - __uint_as_float(b0 & 0xFFFF0000u);
    float r1 = v[2*i+1] - __uint_as_float(b1 & 0xFFFF0000u);
    hw[i] = (b0 >> 16) | (b1 & 0xFFFF0000u);
    lw[i] = (__float_as_uint(r0) >> 16) | (__float_as_uint(r1) & 0xFFFF0000u);
  }
  ((uint4*)h)[0] = *(uint4*)&hw[0];
  ((uint4*)h)[1] = *(uint4*)&hw[4];
  ((uint4*)l)[0] = *(uint4*)&lw[0];
  ((uint4*)l)[1] = *(uint4*)&lw[4];
}

__global__ __launch_bounds__(256, 2) void score_argmin_mfma(
    const float* __restrict__ z, const float* __restrict__ w,
    const float* __restrict__ wsq, unsigned long long* __restrict__ packed) {
  __shared__ ushort Ah[128][LDP];
  __shared__ ushort Al[128][LDP];
  __shared__ ushort Bh[128][LDP];
  __shared__ ushort Bl[128][LDP];
  const int t = threadIdx.x, lane = t & 63, wid = t >> 6;
  const int wm = wid >> 1, wn = wid & 1;
  const int l15 = lane & 15, lg = lane >> 4;
  const int row0 = blockIdx.x * 128;
  const int ks0  = blockIdx.y * (K_N / KSPLIT);
  const int srow = t >> 1, skq = (t & 1) * 16;
  float rmin[16]; int ridx[16];
  #pragma unroll
  for (int e = 0; e < 16; e++) { rmin[e] = 3.4e38f; ridx[e] = 0; }
  for (int ct = 0; ct < COLT; ct++) {
    const int c0 = ks0 + ct * 128;
    f32x4 acc[4][4];
    #pragma unroll
    for (int i = 0; i < 4; i++)
      #pragma unroll
      for (int j = 0; j < 4; j++) acc[i][j] = (f32x4){0.f, 0.f, 0.f, 0.f};
    for (int k0 = 0; k0 < D_N; k0 += 32) {
      __syncthreads();
      stage16(&z[(size_t)(row0 + srow) * D_N + k0 + skq], &Ah[srow][skq], &Al[srow][skq]);
      stage16(&w[(size_t)(c0   + srow) * D_N + k0 + skq], &Bh[srow][skq], &Bl[srow][skq]);
      __syncthreads();
      bf16x8 ah[4], al[4], bh[4], bl[4];
      #pragma unroll
      for (int i = 0; i < 4; i++) {
        ah[i] = *(const bf16x8*)&Ah[wm*64 + i*16 + l15][lg*8];
        al[i] = *(const bf16x8*)&Al[wm*64 + i*16 + l15][lg*8];
        bh[i] = *(const bf16x8*)&Bh[wn*64 + i*16 + l15][lg*8];
        bl[i] = *(const bf16x8*)&Bl[wn*64 + i*16 + l15][lg*8];
      }
      #pragma unroll
      for (int i = 0; i < 4; i++)
        #pragma unroll
        for (int j = 0; j < 4; j++) {
          acc[i][j] = __builtin_amdgcn_mfma_f32_16x16x32_bf16(ah[i], bh[j], acc[i][j], 0, 0, 0);
          acc[i][j] = __builtin_amdgcn_mfma_f32_16x16x32_bf16(ah[i], bl[j], acc[i][j], 0, 0, 0);
          acc[i][j] = __builtin_amdgcn_mfma_f32_16x16x32_bf16(al[i], bh[j], acc[i][j], 0, 0, 0);
        }
    }
    float wq[4];
    #pragma unroll
    for (int j = 0; j < 4; j++) wq[j] = wsq[c0 + wn*64 + j*16 + l15];
    #pragma unroll
    for (int i = 0; i < 4; i++)
      #pragma unroll
      for (int r = 0; r < 4; r++) {
        const int e = i * 4 + r;
        #pragma unroll
        for (int j = 0; j < 4; j++) {
          float dist = wq[j] - 2.0f * acc[i][j][r];
          if (dist < rmin[e]) { rmin[e] = dist; ridx[e] = c0 + wn*64 + j*16 + l15; }
        }
      }
  }
  #pragma unroll
  for (int e = 0; e < 16; e++) {
    float v = rmin[e]; int ix = ridx[e];
    #pragma unroll
    for (int m = 1; m < 16; m <<= 1) {
      float ov = __shfl_xor(v, m, 64);
      int   oi = __shfl_xor(ix, m, 64);
      if (ov < v || (ov == v && oi < ix)) { v = ov; ix = oi; }
    }
    rmin[e] = v; ridx[e] = ix;
  }
  const int s = l15;
  float bv = 0.f; int bi = 0;
  #pragma unroll
  for (int e = 0; e < 16; e++) {
    bool p = (e == s);
    bv = p ? rmin[e] : bv;
    bi = p ? ridx[e] : bi;
  }
  unsigned u = __float_as_uint(bv);
  u = (u & 0x80000000u) ? ~u : (u | 0x80000000u);
  unsigned long long key = ((unsigned long long)u << 32) | (unsigned)bi;
  atomicMin(&packed[row0 + wm*64 + (s >> 2)*16 + lg*4 + (s & 3)], key);
}

// ------------------------------------------- counting-sort segment-sum ----
__global__ __launch_bounds__(256) void count_kernel(
    const unsigned long long* __restrict__ packed, int* __restrict__ cnt,
    float* __restrict__ idxout) {
  int row = blockIdx.x * 256 + threadIdx.x;
  int idx = (int)(packed[row] & 0xFFFFFFFFull);
  idxout[row] = (float)idx;
  atomicAdd(&cnt[idx], 1);
}

__global__ __launch_bounds__(256) void scan_kernel(const int* __restrict__ cnt,
                                                   int* __restrict__ offs,
                                                   int* __restrict__ cursor) {
  int t = threadIdx.x;
  int base = t * 32;
  int local[32];
  int s = 0;
  #pragma unroll
  for (int i = 0; i < 32; i++) { local[i] = s; s += cnt[base + i]; }
  __shared__ int ps[257];
  ps[t + 1] = s;
  if (t == 0) ps[0] = 0;
  __syncthreads();
  if (t == 0) { for (int i = 1; i <= 256; i++) ps[i] += ps[i - 1]; }
  __syncthreads();
  int e = ps[t];
  #pragma unroll
  for (int i = 0; i < 32; i++) {
    int o = e + local[i];
    offs[base + i] = o; cursor[base + i] = o;
  }
  if (t == 255) offs[8192] = ps[256];
}

__global__ __launch_bounds__(256) void scatter_ids(
    const unsigned long long* __restrict__ packed, int* __restrict__ cursor,
    int* __restrict__ rowlist) {
  int row = blockIdx.x * 256 + threadIdx.x;
  int idx = (int)(packed[row] & 0xFFFFFFFFull);
  int pos = atomicAdd(&cursor[idx], 1);
  rowlist[pos] = row;
}

__global__ __launch_bounds__(256) void seg_accum(
    const float* __restrict__ z, const float* __restrict__ edw,
    const float* __restrict__ ecs, const int* __restrict__ offs,
    const int* __restrict__ rowlist, float* __restrict__ nedw_out,
    float* __restrict__ ncs_out) {
  int k = blockIdx.x, t = threadIdx.x;
  int s0 = offs[k], s1 = offs[k + 1];
  float ax = 0.f, ay = 0.f;
  for (int r = s0; r < s1; r++) {
    int row = rowlist[r];
    float2 zv = *(const float2*)&z[(size_t)row * D_N + t * 2];
    ax += zv.x; ay += zv.y;
  }
  float2 ev = *(const float2*)&edw[(size_t)k * D_N + t * 2];
  float2 o;
  o.x = EMA * ev.x + ONE_M_EMA * ax;
  o.y = EMA * ev.y + ONE_M_EMA * ay;
  *(float2*)&nedw_out[(size_t)k * D_N + t * 2] = o;
  if (t == 0) ncs_out[k] = EMA * ecs[k] + ONE_M_EMA * (float)(s1 - s0);
}

// ------------------------------------------------ quantize + loss partial --
__global__ __launch_bounds__(256) void quant_loss(
    const float* __restrict__ z, const float* __restrict__ w,
    const unsigned long long* __restrict__ packed,
    float* __restrict__ qout, float* __restrict__ lpart) {
  int row = blockIdx.x, t = threadIdx.x;
  int idx = (int)(packed[row] & 0xFFFFFFFFull);
  float2 zv = *(const float2*)&z[(size_t)row * D_N + t * 2];
  float2 wv = *(const float2*)&w[(size_t)idx * D_N + t * 2];
  float2 q;
  q.x = zv.x + (wv.x - zv.x);
  q.y = zv.y + (wv.y - zv.y);
  *(float2*)&qout[(size_t)row * D_N + t * 2] = q;
  float dx = zv.x - wv.x, dy = zv.y - wv.y;
  float s = dx * dx + dy * dy;
  #pragma unroll
  for (int off = 32; off; off >>= 1) s += __shfl_down(s, off);
  __shared__ float part[4];
  if ((t & 63) == 0) part[t >> 6] = s;
  __syncthreads();
  if (t == 0) lpart[row] = part[0] + part[1] + part[2] + part[3];
}

// ------------------------------------------------------------- reductions -
__global__ __launch_bounds__(256) void reduce2(const float* __restrict__ ncs_out,
                                               const float* __restrict__ lpart,
                                               float* __restrict__ nsum,
                                               float* __restrict__ loss_sum) {
  int t = threadIdx.x;
  float s1 = 0.f, s2 = 0.f;
  for (int i = t; i < K_N; i += 256) s1 += ncs_out[i];
  for (int i = t; i < B_N; i += 256) s2 += lpart[i];
  #pragma unroll
  for (int off = 32; off; off >>= 1) {
    s1 += __shfl_down(s1, off);
    s2 += __shfl_down(s2, off);
  }
  __shared__ float p1[4], p2[4];
  if ((t & 63) == 0) { p1[t >> 6] = s1; p2[t >> 6] = s2; }
  __syncthreads();
  if (t == 0) {
    nsum[0]     = p1[0] + p1[1] + p1[2] + p1[3];
    loss_sum[0] = p2[0] + p2[1] + p2[2] + p2[3];
  }
}

// fallback-path kernels
__global__ __launch_bounds__(256) void gather_scatter(
    const float* __restrict__ z, const float* __restrict__ w,
    const unsigned long long* __restrict__ packed,
    float* __restrict__ qout, float* __restrict__ idxout,
    float* __restrict__ ncs_out, float* __restrict__ nedw_out,
    float* __restrict__ loss_sum) {
  int row = blockIdx.x;
  int t   = threadIdx.x;
  int idx = (int)(packed[row] & 0xFFFFFFFFull);
  float2 zv = *(const float2*)&z[(size_t)row * D_N + t * 2];
  float2 wv = *(const float2*)&w[(size_t)idx * D_N + t * 2];
  float2 q;
  q.x = zv.x + (wv.x - zv.x);
  q.y = zv.y + (wv.y - zv.y);
  *(float2*)&qout[(size_t)row * D_N + t * 2] = q;
  float dx = zv.x - wv.x, dy = zv.y - wv.y;
  float s = dx*dx + dy*dy;
  #pragma unroll
  for (int off = 32; off; off >>= 1) s += __shfl_down(s, off);
  __shared__ float part[4];
  if ((t & 63) == 0) part[t >> 6] = s;
  __syncthreads();
  if (t == 0) {
    atomicAdd(loss_sum, part[0] + part[1] + part[2] + part[3]);
    atomicAdd(&ncs_out[idx], ONE_M_EMA);
    idxout[row] = (float)idx;
  }
  atomicAdd(&nedw_out[(size_t)idx * D_N + t*2],     ONE_M_EMA * zv.x);
  atomicAdd(&nedw_out[(size_t)idx * D_N + t*2 + 1], ONE_M_EMA * zv.y);
}

__global__ __launch_bounds__(256) void reduce_n(const float* __restrict__ ncs_out,
                                                float* __restrict__ nsum) {
  int t = threadIdx.x;
  float s = 0.f;
  for (int i = t; i < K_N; i += 256) s += ncs_out[i];
  #pragma unroll
  for (int off = 32; off; off >>= 1) s += __shfl_down(s, off);
  __shared__ float part[4];
  if ((t & 63) == 0) part[t >> 6] = s;
  __syncthreads();
  if (t == 0) nsum[0] = part[0] + part[1] + part[2] + part[3];
}

__global__ __launch_bounds__(256) void finalize(
    const float* __restrict__ ncs_out, const float* __restrict__ nedw_out,
    float* __restrict__ nw_out, const float* __restrict__ nsum,
    const float* __restrict__ loss_sum, float* __restrict__ loss_out) {
  size_t i = (size_t)blockIdx.x * 256 + threadIdx.x;
  float n = nsum[0];
  int k = (int)(i >> 9);
  float nv = ncs_out[k];
  float cs = (nv + EPS_) / (n + K_N * EPS_) * n;
  nw_out[i] = nedw_out[i] / cs;
  if (i == 0) loss_out[0] = CCOST * loss_sum[0] / (float)((size_t)B_N * D_N);
}

// ------------------------------------------------------------------ launch -
extern "C" void kernel_launch(void* const* d_in, const int* in_sizes, int n_in,
                              void* d_out, int out_size, void* d_ws, size_t ws_size,
                              hipStream_t stream) {
  const float* z   = (const float*)d_in[0];
  const float* w   = (const float*)d_in[1];
  const float* ecs = (const float*)d_in[2];
  const float* edw = (const float*)d_in[3];

  float* out      = (float*)d_out;
  float* qout     = out;
  float* idxout   = out + (size_t)B_N * D_N;
  float* loss_out = idxout + B_N;
  float* nw_out   = loss_out + 1;
  float* ncs_out  = nw_out + (size_t)K_N * D_N;
  float* nedw_out = ncs_out + K_N;

  unsigned long long* packed = (unsigned long long*)d_ws;
  float* wsq      = (float*)((char*)d_ws + 262144);
  float* loss_sum = (float*)((char*)d_ws + 294912);
  float* nsum     = loss_sum + 1;

  hipMemsetAsync(d_ws, 0xFF, 262144, stream);
  hipMemsetAsync((void*)loss_sum, 0, 8, stream);

  if (ws_size >= WS_NEED) {
    ushort* zp  = (ushort*)((char*)d_ws + ZP_OFF);
    ushort* wp  = (ushort*)((char*)d_ws + WP_OFF);
    int* cnt    = (int*)((char*)d_ws + CNT_OFF);
    int* offs   = (int*)((char*)d_ws + OFFS_OFF);
    int* cursor = (int*)((char*)d_ws + CURS_OFF);
    int* rowl   = (int*)((char*)d_ws + ROWL_OFF);
    float* lpart= (float*)((char*)d_ws + LPART_OFF);

    split_z<<<8192, 256, 0, stream>>>(z, zp);
    split_w<<<2048, 256, 0, stream>>>(w, wp, wsq);   // wsq fused here
    score5<<<dim3(B_N / 64, 4), 64, 0, stream>>>(zp, wp, wsq, packed);
    // aux arrays alias zp (dead after score5) -> init only now
    hipMemsetAsync((void*)cnt, 0, K_N * sizeof(int), stream);
    count_kernel<<<B_N / 256, 256, 0, stream>>>(packed, cnt, idxout);
    scan_kernel<<<1, 256, 0, stream>>>(cnt, offs, cursor);
    scatter_ids<<<B_N / 256, 256, 0, stream>>>(packed, cursor, rowl);
    seg_accum<<<K_N, 256, 0, stream>>>(z, edw, ecs, offs, rowl, nedw_out, ncs_out);
    quant_loss<<<B_N, 256, 0, stream>>>(z, w, packed, qout, lpart);
    reduce2<<<1, 256, 0, stream>>>(ncs_out, lpart, nsum, loss_sum);
  } else {
    prep_kernel<<<2048, 256, 0, stream>>>(w, ecs, wsq, ncs_out);
    prep_nedw<<<4096, 256, 0, stream>>>((const float4*)edw, (float4*)nedw_out);
    score_argmin_mfma<<<dim3(B_N / 128, KSPLIT), 256, 0, stream>>>(z, w, wsq, packed);
    gather_scatter<<<B_N, 256, 0, stream>>>(z, w, packed, qout, idxout,
                                            ncs_out, nedw_out, loss_sum);
    reduce_n<<<1, 256, 0, stream>>>(ncs_out, nsum);
  }

  finalize<<<K_N * D_N / 256, 256, 0, stream>>>(ncs_out, nedw_out, nw_out,
                                                nsum, loss_sum, loss_out);
}

// Round 15
// 1021.752 us; speedup vs baseline: 1.3880x; 1.3880x over previous
//
#include <hip/hip_runtime.h>

#define B_N 32768
#define D_N 512
#define K_N 8192
#define EMA 0.99f
#define ONE_M_EMA 0.01f
#define EPS_ 1e-5f
#define CCOST 0.25f

// ws layout (fast path):
// [0, 262144)            : u64 packed[B_N]  (low32 = idx), init 0xFF
// [262144, 294912)       : float wsq[K_N]
// [294912, 294920)       : float loss_sum, n_sum
// [295936, +67108864)    : ushort zp[32][32768][32]  {hi:0-15, lo:16-31}, chunk-XOR swizzled
// [67404800, +16777216)  : ushort wp[32][8192][32]   {hi:0-15, lo:16-31}
// Logical K' = 1536 = 48 slices; z sections [hi|hi|lo], w sections [hi|lo|hi]
// realized by slice->physical mapping at stage time.
#define ZP_OFF 295936ull
#define WP_OFF 67404800ull
#define WS_NEED (WP_OFF + 16777216ull)
#define CNT_OFF    295936ull
#define OFFS_OFF   332800ull
#define CURS_OFF   365568ull
#define ROWL_OFF   398336ull
#define LPART_OFF  529408ull

typedef __attribute__((ext_vector_type(8))) short bf16x8;
typedef __attribute__((ext_vector_type(4))) float f32x4;

// ---------------------------------------------------------------- prep ----
// (fallback path only; fast path gets wsq from split_w)
__global__ __launch_bounds__(256) void prep_kernel(const float* __restrict__ w,
                                                   const float* __restrict__ ecs,
                                                   float* __restrict__ wsq,
                                                   float* __restrict__ ncs_out) {
  int row  = blockIdx.x * 4 + (threadIdx.x >> 6);
  int lane = threadIdx.x & 63;
  const float* p = w + (size_t)row * D_N + lane * 8;
  float4 a = *(const float4*)p;
  float4 b = *(const float4*)(p + 4);
  float s = a.x*a.x + a.y*a.y + a.z*a.z + a.w*a.w
          + b.x*b.x + b.y*b.y + b.z*b.z + b.w*b.w;
  #pragma unroll
  for (int off = 32; off; off >>= 1) s += __shfl_down(s, off);
  if (lane == 0) wsq[row] = s;

  int gid = blockIdx.x * 256 + threadIdx.x;
  if (gid < K_N) ncs_out[gid] = EMA * ecs[gid];
}

__global__ __launch_bounds__(256) void prep_nedw(const float4* __restrict__ edw,
                                                 float4* __restrict__ nedw) {
  int i = blockIdx.x * 256 + threadIdx.x;
  float4 v = edw[i];
  v.x *= EMA; v.y *= EMA; v.z *= EMA; v.w *= EMA;
  nedw[i] = v;
}

// ------------------------------------------------------------ pre-split ---
// x[R][512] f32 -> xp[32][R][32] bf16: physical sec0 = hi slices, sec1 = lo.
// 16B chunk stored at (c ^ ((row>>1)&3)) -- ds_read-side XOR swizzle baked in.
__global__ __launch_bounds__(256) void split_z(const float* __restrict__ x,
                                               ushort* __restrict__ xp) {
  int g   = blockIdx.x * 256 + threadIdx.x;
  int row = g >> 6, c = g & 63;
  const float* src = x + (size_t)row * 512 + c * 8;
  float v[8];
  *(float4*)&v[0] = *(const float4*)&src[0];
  *(float4*)&v[4] = *(const float4*)&src[4];
  uint hw[4], lw[4];
  #pragma unroll
  for (int i = 0; i < 4; i++) {
    uint b0 = __float_as_uint(v[2*i]);
    uint b1 = __float_as_uint(v[2*i+1]);
    float r0 = v[2*i]   - __uint_as_float(b0 & 0xFFFF0000u);
    float r1 = v[2*i+1] - __uint_as_float(b1 & 0xFFFF0000u);
    hw[i] = (b0 >> 16) | (b1 & 0xFFFF0000u);
    lw[i] = (__float_as_uint(r0) >> 16) | (__float_as_uint(r1) & 0xFFFF0000u);
  }
  int si  = c >> 2;
  int p   = (c & 3) ^ ((row >> 1) & 3);
  size_t sstr = (size_t)B_N * 32;
  size_t base = (size_t)row * 32 + (size_t)p * 8;
  *(uint4*)&xp[(size_t)si * sstr + base]        = (uint4){hw[0], hw[1], hw[2], hw[3]};
  *(uint4*)&xp[(size_t)(16 + si) * sstr + base] = (uint4){lw[0], lw[1], lw[2], lw[3]};
}

// split_w also computes wsq (fused w pass; one wave per row)
__global__ __launch_bounds__(256) void split_w(const float* __restrict__ x,
                                               ushort* __restrict__ xp,
                                               float* __restrict__ wsq) {
  int g   = blockIdx.x * 256 + threadIdx.x;
  int row = g >> 6, c = g & 63;
  const float* src = x + (size_t)row * 512 + c * 8;
  float v[8];
  *(float4*)&v[0] = *(const float4*)&src[0];
  *(float4*)&v[4] = *(const float4*)&src[4];
  uint hw[4], lw[4]; float w2 = 0.f;
  #pragma unroll
  for (int i = 0; i < 4; i++) {
    uint b0 = __float_as_uint(v[2*i]);
    uint b1 = __float_as_uint(v[2*i+1]);
    float r0 = v[2*i]   - __uint_as_float(b0 & 0xFFFF0000u);
    float r1 = v[2*i+1] - __uint_as_float(b1 & 0xFFFF0000u);
    hw[i] = (b0 >> 16) | (b1 & 0xFFFF0000u);
    lw[i] = (__float_as_uint(r0) >> 16) | (__float_as_uint(r1) & 0xFFFF0000u);
    w2 += v[2*i]*v[2*i] + v[2*i+1]*v[2*i+1];
  }
  int si  = c >> 2;
  int p   = (c & 3) ^ ((row >> 1) & 3);
  size_t sstr = (size_t)K_N * 32;
  size_t base = (size_t)row * 32 + (size_t)p * 8;
  *(uint4*)&xp[(size_t)si * sstr + base]        = (uint4){hw[0], hw[1], hw[2], hw[3]};
  *(uint4*)&xp[(size_t)(16 + si) * sstr + base] = (uint4){lw[0], lw[1], lw[2], lw[3]};
  #pragma unroll
  for (int off = 32; off; off >>= 1) w2 += __shfl_down(w2, off);
  if (c == 0) wsq[row] = w2;
}

// --------------------------------------------------------- score+argmin ---
// 256x256 tile, 8 waves (2M x 4N, 128x64 each), BK=32 ring of 4 LDS slots.
// TWO slices per phase: compute (2P,2P+1) from E/O regs; reload E after its
// last MFMA read (WAR via register deps); stage slices (2P+4,2P+5) into slots
// (2P)&3,(2P+1)&3; one lgkm(0)+vmcnt(0)+barrier per phase.
constexpr int COLT2 = 8;

#define GLDS(SRC, DST) __builtin_amdgcn_global_load_lds((const unsigned int*)(SRC), (unsigned int*)(DST), 16, 0, 0)

// stage one logical slice S (0..47 within col-tile ctf) into slot SL
#define STAGE1(S, SL)                                                          \
  {                                                                            \
    const int s__ = (S);                                                       \
    const int zsl_ = (s__ < 32) ? (s__ & 15) : (s__ - 16);  /* [hi|hi|lo] */   \
    const int wsl_ = (s__ < 32) ? s__ : (s__ - 32);         /* [hi|lo|hi] */   \
    GLDS(zA + (size_t)zsl_ * 2097152,        (char*)As[SL] + t * 16);          \
    GLDS(zA + (size_t)zsl_ * 2097152 + 8192, (char*)As[SL] + 8192 + t * 16);   \
    const size_t wOfs_ = (size_t)wsl_ * 524288 + (size_t)ctf * 16384;          \
    GLDS(wB + wOfs_,        (char*)Bs[SL] + t * 16);                           \
    GLDS(wB + wOfs_ + 8192, (char*)Bs[SL] + 8192 + t * 16);                    \
  }

#define LOADFRAG(AX, BX, G)                                                    \
  {                                                                            \
    const char* Ab_ = (const char*)As[(G) & 3] + aoff;                         \
    const char* Bb_ = (const char*)Bs[(G) & 3] + boff;                         \
    _Pragma("unroll")                                                          \
    for (int i_ = 0; i_ < 8; i_++) AX[i_] = *(const bf16x8*)(Ab_ + i_ * 1024); \
    _Pragma("unroll")                                                          \
    for (int j_ = 0; j_ < 4; j_++) BX[j_] = *(const bf16x8*)(Bb_ + j_ * 1024); \
  }

#define MFMABLK(AX, BX)                                                        \
  {                                                                            \
    __builtin_amdgcn_s_setprio(1);                                             \
    _Pragma("unroll")                                                          \
    for (int i_ = 0; i_ < 8; i_++)                                             \
      _Pragma("unroll")                                                        \
      for (int j_ = 0; j_ < 4; j_++)                                           \
        acc[i_][j_] = __builtin_amdgcn_mfma_f32_16x16x32_bf16(AX[i_], BX[j_],  \
                                                        acc[i_][j_], 0, 0, 0); \
    __builtin_amdgcn_s_setprio(0);                                             \
  }

// phase over slices (G2, G2+1); G2 even, global in [0,384)
#define PHASE2(G2)                                                             \
  {                                                                            \
    const int g2_ = (G2);                                                      \
    if (g2_ + 4 <= 383) {          /* stage slices g2+4, g2+5 */               \
      STAGE1(sf,     sf & 3)                                                   \
      STAGE1(sf + 1, (sf + 1) & 3)                                             \
      sf += 2; if (sf == 48) { sf = 0; ctf++; }                                \
    }                                                                          \
    MFMABLK(aE, bE)                /* slice g2 */                              \
    if (g2_ + 2 <= 383) LOADFRAG(aE, bE, g2_ + 2)  /* WAR: after E's reads */  \
    MFMABLK(aO, bO)                /* slice g2+1 */                            \
    if (g2_ + 3 <= 383) LOADFRAG(aO, bO, g2_ + 3)                              \
    asm volatile("s_waitcnt lgkmcnt(0)" ::: "memory");                         \
    asm volatile("s_waitcnt vmcnt(0)" ::: "memory");                           \
    __builtin_amdgcn_s_barrier();                                              \
    __builtin_amdgcn_sched_barrier(0);                                         \
  }

__global__ __launch_bounds__(512, 2) void score3r(
    const ushort* __restrict__ zp, const ushort* __restrict__ wp,
    const float* __restrict__ wsq, unsigned long long* __restrict__ packed) {
  __shared__ ushort As[4][8192];             // 4 slots x [256 rows][32 sh]
  __shared__ ushort Bs[4][8192];
  __shared__ float wsqs[2048];
  __shared__ unsigned long long best2[256][4];

  const int t = threadIdx.x, lane = t & 63, wid = t >> 6;
  const int wm = wid >> 2, wn = wid & 3;     // 2M x 4N wave grid
  const int l15 = lane & 15, lg = (lane >> 4) & 3;
  const int row0 = blockIdx.x * 256;
  const int cg0  = blockIdx.y * 2048;

  const char* zA = (const char*)zp + ((size_t)(row0 + (t >> 2)) * 64 + (size_t)(t & 3) * 16);
  const char* wB = (const char*)wp + ((size_t)(cg0  + (t >> 2)) * 64 + (size_t)(t & 3) * 16);

  const int swz  = (l15 >> 1) & 3;
  const int aoff = (wm * 128 + l15) * 64 + ((lg ^ swz) * 16);
  const int boff = (wn * 64  + l15) * 64 + ((lg ^ swz) * 16);

  { float4 v = *(const float4*)&wsq[cg0 + t * 4]; *(float4*)&wsqs[t * 4] = v; }
  if (t < 256) { best2[t][0] = ~0ull; best2[t][1] = ~0ull; best2[t][2] = ~0ull; best2[t][3] = ~0ull; }
  __syncthreads();                            // wsqs/best2 visible, full drain

  int sf = 4, ctf = 0;                        // next logical slice to stage

  // prologue: stage slices 0..3 (slots 0..3; identity mapping since <16)
  #pragma unroll
  for (int s0 = 0; s0 < 4; s0++) {
    GLDS(zA + (size_t)s0 * 2097152,        (char*)As[s0] + t * 16);
    GLDS(zA + (size_t)s0 * 2097152 + 8192, (char*)As[s0] + 8192 + t * 16);
    GLDS(wB + (size_t)s0 * 524288,         (char*)Bs[s0] + t * 16);
    GLDS(wB + (size_t)s0 * 524288 + 8192,  (char*)Bs[s0] + 8192 + t * 16);
  }
  asm volatile("s_waitcnt vmcnt(0)" ::: "memory");    // all 4 slots landed
  __builtin_amdgcn_s_barrier();
  __builtin_amdgcn_sched_barrier(0);

  bf16x8 aE[8], bE[4], aO[8], bO[4];
  LOADFRAG(aE, bE, 0)
  LOADFRAG(aO, bO, 1)
  asm volatile("s_waitcnt lgkmcnt(0)" ::: "memory");  // frags(0),(1) drained
  __builtin_amdgcn_s_barrier();
  __builtin_amdgcn_sched_barrier(0);

  for (int ct = 0; ct < COLT2; ct++) {
    f32x4 acc[8][4];
    #pragma unroll
    for (int i = 0; i < 8; i++)
      #pragma unroll
      for (int j = 0; j < 4; j++) acc[i][j] = (f32x4){0.f, 0.f, 0.f, 0.f};

    for (int p = 0; p < 24; p++) {            // 24 phases x 2 slices = 48
      PHASE2(ct * 48 + 2 * p)
    }

    // ---- epilogue: distances + argmin for this col-tile
    float rv[32]; int rx[32];
    #pragma unroll
    for (int i = 0; i < 8; i++)
      #pragma unroll
      for (int r = 0; r < 4; r++) {
        float bvv = 3.4e38f; int bii = 0;
        #pragma unroll
        for (int j = 0; j < 4; j++) {
          float wq = wsqs[ct * 256 + wn * 64 + j * 16 + l15];
          float dist = wq - 2.0f * acc[i][j][r];
          int c = cg0 + ct * 256 + wn * 64 + j * 16 + l15;
          if (dist < bvv) { bvv = dist; bii = c; }   // j ascending: first idx wins
        }
        rv[i * 4 + r] = bvv; rx[i * 4 + r] = bii;
      }
    #pragma unroll
    for (int e = 0; e < 32; e++) {
      float v = rv[e]; int ix = rx[e];
      #pragma unroll
      for (int m = 1; m < 16; m <<= 1) {
        float ov = __shfl_xor(v, m, 64);
        int   oi = __shfl_xor(ix, m, 64);
        if (ov < v || (ov == v && oi < ix)) { v = ov; ix = oi; }
      }
      rv[e] = v; rx[e] = ix;
    }
    #pragma unroll
    for (int half = 0; half < 2; half++) {     // lane l15 commits entries l15, l15+16
      const int e0 = l15 + half * 16;
      float bvv = 0.f; int bii = 0;
      #pragma unroll
      for (int e = 0; e < 32; e++) {            // static-index select (rule #20)
        bool p2 = (e == e0);
        bvv = p2 ? rv[e] : bvv; bii = p2 ? rx[e] : bii;
      }
      unsigned u = __float_as_uint(bvv);
      u = (u & 0x80000000u) ? ~u : (u | 0x80000000u);
      unsigned long long key = ((unsigned long long)u << 32) | (unsigned)bii;
      const int rowl = wm * 128 + (e0 >> 2) * 16 + lg * 4 + (e0 & 3);
      unsigned long long cur = best2[rowl][wn];  // single-writer slot: no atomic
      if (key < cur) best2[rowl][wn] = key;
    }
  }

  __syncthreads();
  if (t < 256) {
    unsigned long long k0 = best2[t][0], k1 = best2[t][1];
    unsigned long long k2 = best2[t][2], k3 = best2[t][3];
    unsigned long long m0 = k0 < k1 ? k0 : k1;
    unsigned long long m1 = k2 < k3 ? k2 : k3;
    atomicMin(&packed[row0 + t], m0 < m1 ? m0 : m1);
  }
}

// ---------------------------------------- fallback score (round-2 kernel) --
constexpr int LDP = 40;
constexpr int KSPLIT = 8, COLT = K_N / KSPLIT / 128;
__device__ __forceinline__ void stage16(const float* __restrict__ g,
                                        ushort* __restrict__ h,
                                        ushort* __restrict__ l) {
  float v[16];
  *(float4*)&v[0]  = *(const float4*)&g[0];
  *(float4*)&v[4]  = *(const float4*)&g[4];
  *(float4*)&v[8]  = *(const float4*)&g[8];
  *(float4*)&v[12] = *(const float4*)&g[12];
  uint hw[8], lw[8];
  #pragma unroll
  for (int i = 0; i < 8; i++) {
    uint b0 = __float_as_uint(v[2*i]);
    uint b1 = __float_as_uint(v[2*i+1]);
    float r0 = v[2*i]   - __uint_as_float(b0 & 0xFFFF0000u);
    float r1 = v[2*i+1] - __uint_as_float(b1 & 0xFFFF0000u);
    hw[i] = (b0 >> 16) | (b1 & 0xFFFF0000u);
    lw[i] = (__float_as_uint(r0) >> 16) | (__float_as_uint(r1) & 0xFFFF0000u);
  }
  ((uint4*)h)[0] = *(uint4*)&hw[0];
  ((uint4*)h)[1] = *(uint4*)&hw[4];
  ((uint4*)l)[0] = *(uint4*)&lw[0];
  ((uint4*)l)[1] = *(uint4*)&lw[4];
}

__global__ __launch_bounds__(256, 2) void score_argmin_mfma(
    const float* __restrict__ z, const float* __restrict__ w,
    const float* __restrict__ wsq, unsigned long long* __restrict__ packed) {
  __shared__ ushort Ah[128][LDP];
  __shared__ ushort Al[128][LDP];
  __shared__ ushort Bh[128][LDP];
  __shared__ ushort Bl[128][LDP];
  const int t = threadIdx.x, lane = t & 63, wid = t >> 6;
  const int wm = wid >> 1, wn = wid & 1;
  const int l15 = lane & 15, lg = lane >> 4;
  const int row0 = blockIdx.x * 128;
  const int ks0  = blockIdx.y * (K_N / KSPLIT);
  const int srow = t >> 1, skq = (t & 1) * 16;
  float rmin[16]; int ridx[16];
  #pragma unroll
  for (int e = 0; e < 16; e++) { rmin[e] = 3.4e38f; ridx[e] = 0; }
  for (int ct = 0; ct < COLT; ct++) {
    const int c0 = ks0 + ct * 128;
    f32x4 acc[4][4];
    #pragma unroll
    for (int i = 0; i < 4; i++)
      #pragma unroll
      for (int j = 0; j < 4; j++) acc[i][j] = (f32x4){0.f, 0.f, 0.f, 0.f};
    for (int k0 = 0; k0 < D_N; k0 += 32) {
      __syncthreads();
      stage16(&z[(size_t)(row0 + srow) * D_N + k0 + skq], &Ah[srow][skq], &Al[srow][skq]);
      stage16(&w[(size_t)(c0   + srow) * D_N + k0 + skq], &Bh[srow][skq], &Bl[srow][skq]);
      __syncthreads();
      bf16x8 ah[4], al[4], bh[4], bl[4];
      #pragma unroll
      for (int i = 0; i < 4; i++) {
        ah[i] = *(const bf16x8*)&Ah[wm*64 + i*16 + l15][lg*8];
        al[i] = *(const bf16x8*)&Al[wm*64 + i*16 + l15][lg*8];
        bh[i] = *(const bf16x8*)&Bh[wn*64 + i*16 + l15][lg*8];
        bl[i] = *(const bf16x8*)&Bl[wn*64 + i*16 + l15][lg*8];
      }
      #pragma unroll
      for (int i = 0; i < 4; i++)
        #pragma unroll
        for (int j = 0; j < 4; j++) {
          acc[i][j] = __builtin_amdgcn_mfma_f32_16x16x32_bf16(ah[i], bh[j], acc[i][j], 0, 0, 0);
          acc[i][j] = __builtin_amdgcn_mfma_f32_16x16x32_bf16(ah[i], bl[j], acc[i][j], 0, 0, 0);
          acc[i][j] = __builtin_amdgcn_mfma_f32_16x16x32_bf16(al[i], bh[j], acc[i][j], 0, 0, 0);
        }
    }
    float wq[4];
    #pragma unroll
    for (int j = 0; j < 4; j++) wq[j] = wsq[c0 + wn*64 + j*16 + l15];
    #pragma unroll
    for (int i = 0; i < 4; i++)
      #pragma unroll
      for (int r = 0; r < 4; r++) {
        const int e = i * 4 + r;
        #pragma unroll
        for (int j = 0; j < 4; j++) {
          float dist = wq[j] - 2.0f * acc[i][j][r];
          if (dist < rmin[e]) { rmin[e] = dist; ridx[e] = c0 + wn*64 + j*16 + l15; }
        }
      }
  }
  #pragma unroll
  for (int e = 0; e < 16; e++) {
    float v = rmin[e]; int ix = ridx[e];
    #pragma unroll
    for (int m = 1; m < 16; m <<= 1) {
      float ov = __shfl_xor(v, m, 64);
      int   oi = __shfl_xor(ix, m, 64);
      if (ov < v || (ov == v && oi < ix)) { v = ov; ix = oi; }
    }
    rmin[e] = v; ridx[e] = ix;
  }
  const int s = l15;
  float bv = 0.f; int bi = 0;
  #pragma unroll
  for (int e = 0; e < 16; e++) {
    bool p = (e == s);
    bv = p ? rmin[e] : bv;
    bi = p ? ridx[e] : bi;
  }
  unsigned u = __float_as_uint(bv);
  u = (u & 0x80000000u) ? ~u : (u | 0x80000000u);
  unsigned long long key = ((unsigned long long)u << 32) | (unsigned)bi;
  atomicMin(&packed[row0 + wm*64 + (s >> 2)*16 + lg*4 + (s & 3)], key);
}

// ------------------------------------------- counting-sort segment-sum ----
__global__ __launch_bounds__(256) void count_kernel(
    const unsigned long long* __restrict__ packed, int* __restrict__ cnt,
    float* __restrict__ idxout) {
  int row = blockIdx.x * 256 + threadIdx.x;
  int idx = (int)(packed[row] & 0xFFFFFFFFull);
  idxout[row] = (float)idx;
  atomicAdd(&cnt[idx], 1);
}

__global__ __launch_bounds__(256) void scan_kernel(const int* __restrict__ cnt,
                                                   int* __restrict__ offs,
                                                   int* __restrict__ cursor) {
  int t = threadIdx.x;
  int base = t * 32;
  int local[32];
  int s = 0;
  #pragma unroll
  for (int i = 0; i < 32; i++) { local[i] = s; s += cnt[base + i]; }
  __shared__ int ps[257];
  ps[t + 1] = s;
  if (t == 0) ps[0] = 0;
  __syncthreads();
  if (t == 0) { for (int i = 1; i <= 256; i++) ps[i] += ps[i - 1]; }
  __syncthreads();
  int e = ps[t];
  #pragma unroll
  for (int i = 0; i < 32; i++) {
    int o = e + local[i];
    offs[base + i] = o; cursor[base + i] = o;
  }
  if (t == 255) offs[8192] = ps[256];
}

__global__ __launch_bounds__(256) void scatter_ids(
    const unsigned long long* __restrict__ packed, int* __restrict__ cursor,
    int* __restrict__ rowlist) {
  int row = blockIdx.x * 256 + threadIdx.x;
  int idx = (int)(packed[row] & 0xFFFFFFFFull);
  int pos = atomicAdd(&cursor[idx], 1);
  rowlist[pos] = row;
}

__global__ __launch_bounds__(256) void seg_accum(
    const float* __restrict__ z, const float* __restrict__ edw,
    const float* __restrict__ ecs, const int* __restrict__ offs,
    const int* __restrict__ rowlist, float* __restrict__ nedw_out,
    float* __restrict__ ncs_out) {
  int k = blockIdx.x, t = threadIdx.x;
  int s0 = offs[k], s1 = offs[k + 1];
  float ax = 0.f, ay = 0.f;
  for (int r = s0; r < s1; r++) {
    int row = rowlist[r];
    float2 zv = *(const float2*)&z[(size_t)row * D_N + t * 2];
    ax += zv.x; ay += zv.y;
  }
  float2 ev = *(const float2*)&edw[(size_t)k * D_N + t * 2];
  float2 o;
  o.x = EMA * ev.x + ONE_M_EMA * ax;
  o.y = EMA * ev.y + ONE_M_EMA * ay;
  *(float2*)&nedw_out[(size_t)k * D_N + t * 2] = o;
  if (t == 0) ncs_out[k] = EMA * ecs[k] + ONE_M_EMA * (float)(s1 - s0);
}

// ------------------------------------------------ quantize + loss partial --
__global__ __launch_bounds__(256) void quant_loss(
    const float* __restrict__ z, const float* __restrict__ w,
    const unsigned long long* __restrict__ packed,
    float* __restrict__ qout, float* __restrict__ lpart) {
  int row = blockIdx.x, t = threadIdx.x;
  int idx = (int)(packed[row] & 0xFFFFFFFFull);
  float2 zv = *(const float2*)&z[(size_t)row * D_N + t * 2];
  float2 wv = *(const float2*)&w[(size_t)idx * D_N + t * 2];
  float2 q;
  q.x = zv.x + (wv.x - zv.x);
  q.y = zv.y + (wv.y - zv.y);
  *(float2*)&qout[(size_t)row * D_N + t * 2] = q;
  float dx = zv.x - wv.x, dy = zv.y - wv.y;
  float s = dx * dx + dy * dy;
  #pragma unroll
  for (int off = 32; off; off >>= 1) s += __shfl_down(s, off);
  __shared__ float part[4];
  if ((t & 63) == 0) part[t >> 6] = s;
  __syncthreads();
  if (t == 0) lpart[row] = part[0] + part[1] + part[2] + part[3];
}

// ------------------------------------------------------------- reductions -
__global__ __launch_bounds__(256) void reduce2(const float* __restrict__ ncs_out,
                                               const float* __restrict__ lpart,
                                               float* __restrict__ nsum,
                                               float* __restrict__ loss_sum) {
  int t = threadIdx.x;
  float s1 = 0.f, s2 = 0.f;
  for (int i = t; i < K_N; i += 256) s1 += ncs_out[i];
  for (int i = t; i < B_N; i += 256) s2 += lpart[i];
  #pragma unroll
  for (int off = 32; off; off >>= 1) {
    s1 += __shfl_down(s1, off);
    s2 += __shfl_down(s2, off);
  }
  __shared__ float p1[4], p2[4];
  if ((t & 63) == 0) { p1[t >> 6] = s1; p2[t >> 6] = s2; }
  __syncthreads();
  if (t == 0) {
    nsum[0]     = p1[0] + p1[1] + p1[2] + p1[3];
    loss_sum[0] = p2[0] + p2[1] + p2[2] + p2[3];
  }
}

// fallback-path kernels
__global__ __launch_bounds__(256) void gather_scatter(
    const float* __restrict__ z, const float* __restrict__ w,
    const unsigned long long* __restrict__ packed,
    float* __restrict__ qout, float* __restrict__ idxout,
    float* __restrict__ ncs_out, float* __restrict__ nedw_out,
    float* __restrict__ loss_sum) {
  int row = blockIdx.x;
  int t   = threadIdx.x;
  int idx = (int)(packed[row] & 0xFFFFFFFFull);
  float2 zv = *(const float2*)&z[(size_t)row * D_N + t * 2];
  float2 wv = *(const float2*)&w[(size_t)idx * D_N + t * 2];
  float2 q;
  q.x = zv.x + (wv.x - zv.x);
  q.y = zv.y + (wv.y - zv.y);
  *(float2*)&qout[(size_t)row * D_N + t * 2] = q;
  float dx = zv.x - wv.x, dy = zv.y - wv.y;
  float s = dx*dx + dy*dy;
  #pragma unroll
  for (int off = 32; off; off >>= 1) s += __shfl_down(s, off);
  __shared__ float part[4];
  if ((t & 63) == 0) part[t >> 6] = s;
  __syncthreads();
  if (t == 0) {
    atomicAdd(loss_sum, part[0] + part[1] + part[2] + part[3]);
    atomicAdd(&ncs_out[idx], ONE_M_EMA);
    idxout[row] = (float)idx;
  }
  atomicAdd(&nedw_out[(size_t)idx * D_N + t*2],     ONE_M_EMA * zv.x);
  atomicAdd(&nedw_out[(size_t)idx * D_N + t*2 + 1], ONE_M_EMA * zv.y);
}

__global__ __launch_bounds__(256) void reduce_n(const float* __restrict__ ncs_out,
                                                float* __restrict__ nsum) {
  int t = threadIdx.x;
  float s = 0.f;
  for (int i = t; i < K_N; i += 256) s += ncs_out[i];
  #pragma unroll
  for (int off = 32; off; off >>= 1) s += __shfl_down(s, off);
  __shared__ float part[4];
  if ((t & 63) == 0) part[t >> 6] = s;
  __syncthreads();
  if (t == 0) nsum[0] = part[0] + part[1] + part[2] + part[3];
}

__global__ __launch_bounds__(256) void finalize(
    const float* __restrict__ ncs_out, const float* __restrict__ nedw_out,
    float* __restrict__ nw_out, const float* __restrict__ nsum,
    const float* __restrict__ loss_sum, float* __restrict__ loss_out) {
  size_t i = (size_t)blockIdx.x * 256 + threadIdx.x;
  float n = nsum[0];
  int k = (int)(i >> 9);
  float nv = ncs_out[k];
  float cs = (nv + EPS_) / (n + K_N * EPS_) * n;
  nw_out[i] = nedw_out[i] / cs;
  if (i == 0) loss_out[0] = CCOST * loss_sum[0] / (float)((size_t)B_N * D_N);
}

// ------------------------------------------------------------------ launch -
extern "C" void kernel_launch(void* const* d_in, const int* in_sizes, int n_in,
                              void* d_out, int out_size, void* d_ws, size_t ws_size,
                              hipStream_t stream) {
  const float* z   = (const float*)d_in[0];
  const float* w   = (const float*)d_in[1];
  const float* ecs = (const float*)d_in[2];
  const float* edw = (const float*)d_in[3];

  float* out      = (float*)d_out;
  float* qout     = out;
  float* idxout   = out + (size_t)B_N * D_N;
  float* loss_out = idxout + B_N;
  float* nw_out   = loss_out + 1;
  float* ncs_out  = nw_out + (size_t)K_N * D_N;
  float* nedw_out = ncs_out + K_N;

  unsigned long long* packed = (unsigned long long*)d_ws;
  float* wsq      = (float*)((char*)d_ws + 262144);
  float* loss_sum = (float*)((char*)d_ws + 294912);
  float* nsum     = loss_sum + 1;

  hipMemsetAsync(d_ws, 0xFF, 262144, stream);
  hipMemsetAsync((void*)loss_sum, 0, 8, stream);

  if (ws_size >= WS_NEED) {
    ushort* zp  = (ushort*)((char*)d_ws + ZP_OFF);
    ushort* wp  = (ushort*)((char*)d_ws + WP_OFF);
    int* cnt    = (int*)((char*)d_ws + CNT_OFF);
    int* offs   = (int*)((char*)d_ws + OFFS_OFF);
    int* cursor = (int*)((char*)d_ws + CURS_OFF);
    int* rowl   = (int*)((char*)d_ws + ROWL_OFF);
    float* lpart= (float*)((char*)d_ws + LPART_OFF);

    split_z<<<8192, 256, 0, stream>>>(z, zp);
    split_w<<<2048, 256, 0, stream>>>(w, wp, wsq);   // wsq fused here
    score3r<<<dim3(128, 4), 512, 0, stream>>>(zp, wp, wsq, packed);
    // aux arrays alias zp (dead after score3r) -> init only now
    hipMemsetAsync((void*)cnt, 0, K_N * sizeof(int), stream);
    count_kernel<<<B_N / 256, 256, 0, stream>>>(packed, cnt, idxout);
    scan_kernel<<<1, 256, 0, stream>>>(cnt, offs, cursor);
    scatter_ids<<<B_N / 256, 256, 0, stream>>>(packed, cursor, rowl);
    seg_accum<<<K_N, 256, 0, stream>>>(z, edw, ecs, offs, rowl, nedw_out, ncs_out);
    quant_loss<<<B_N, 256, 0, stream>>>(z, w, packed, qout, lpart);
    reduce2<<<1, 256, 0, stream>>>(ncs_out, lpart, nsum, loss_sum);
  } else {
    prep_kernel<<<2048, 256, 0, stream>>>(w, ecs, wsq, ncs_out);
    prep_nedw<<<4096, 256, 0, stream>>>((const float4*)edw, (float4*)nedw_out);
    score_argmin_mfma<<<dim3(B_N / 128, KSPLIT), 256, 0, stream>>>(z, w, wsq, packed);
    gather_scatter<<<B_N, 256, 0, stream>>>(z, w, packed, qout, idxout,
                                            ncs_out, nedw_out, loss_sum);
    reduce_n<<<1, 256, 0, stream>>>(ncs_out, nsum);
  }

  finalize<<<K_N * D_N / 256, 256, 0, stream>>>(ncs_out, nedw_out, nw_out,
                                                nsum, loss_sum, loss_out);
}